// Round 11
// baseline (293.641 us; speedup 1.0000x reference)
//
#include <hip/hip_runtime.h>

#define HID 10
#define STEPS 512

typedef __attribute__((ext_vector_type(2))) float v2f;
typedef __attribute__((ext_vector_type(4))) float v4f;

// broadcast lane ((lane&0x10)|F) within each 32-lane half -> all lanes of each 16-group
// (one-time use: t=0 peel)
template<int F>
static __device__ __forceinline__ float swz(float v) {
    return __int_as_float(__builtin_amdgcn_ds_swizzle(__float_as_int(v), (F << 5) | 0x10));
}

// Lane-parallel fused GRU decoder, 1 feature per lane, EIGHT batches per wave
// via BATCH-PAIR v2f PACKING: lane state h = {hA, hB} (batches bA, bB=bA+4).
// v11 rationale: v7's 723 cyc/SIMD-step = 434 issue + 290 stall; stagger (R7/R10)
// and in-wave dual-stream (R8/R9) both falsified. This version halves BOTH axes
// per batch at the DATA level: every pk_fma computes two batches (same scalar
// weight duplicated into both halves), so 50 pk_fma serve 8 batches with NO
// fold ops, and the pairing lives inside each instruction — the compiler cannot
// serialize it (R8/R9's failure). DS per wave-step: 1 ds_write_b64 + 5
// broadcast ds_read_b128 for 8 batches. Rows padded to 18 v2f (144 B) ->
// group bases hit banks {0,4,8,12}: reads conflict-free. Grid 1024 = 1
// wave/SIMD: no convoy partner; period ~ max(issue ~205, chain ~230).
__attribute__((amdgpu_waves_per_eu(1, 1)))
__global__ __launch_bounds__(64) void gru_decoder_kernel(
    const float* __restrict__ hidden, const float* __restrict__ w_ih,
    const float* __restrict__ w_hh, const float* __restrict__ b_ih,
    const float* __restrict__ b_hh, const float* __restrict__ l1_w,
    const float* __restrict__ l1_b, const float* __restrict__ l2_w,
    const float* __restrict__ l2_b, float* __restrict__ out)
{
    __shared__ float sWx[640];   // l2_w @ l1_w (64x10)
    __shared__ float sbx[64];    // l2_w @ l1_b + l2_b
    __shared__ float sWgi[300];  // w_ih @ Wx (30x10)
    __shared__ float sbgi[30];   // b_ih + w_ih @ bx
    __shared__ float sWhh[300];  // w_hh copy (t=0 peel + weight build)
    __shared__ float sHp[144];   // 4 groups x 18 v2f rows (pair staging, 144B stride)

    const int lane = threadIdx.x;
    const int f    = lane & 15;
    const int g    = lane >> 4;
    const int bA   = blockIdx.x * 8 + g;
    const int bB   = bA + 4;
    const bool ok  = (f < HID);
    const int fi   = ok ? f : 0;          // clamped index for safe reads

    // ---- preamble: fused weights (fp32, cooperative) ----
    for (int e = lane; e < 640; e += 64) {
        int i = e / 10, j = e - i * 10;
        float acc = 0.f;
        #pragma unroll
        for (int k = 0; k < 10; ++k) acc += l2_w[i * 10 + k] * l1_w[k * 10 + j];
        sWx[e] = acc;
    }
    {
        float acc = l2_b[lane];
        #pragma unroll
        for (int k = 0; k < 10; ++k) acc += l2_w[lane * 10 + k] * l1_b[k];
        sbx[lane] = acc;
    }
    for (int e = lane; e < 300; e += 64) sWhh[e] = w_hh[e];
    __syncthreads();
    for (int e = lane; e < 300; e += 64) {
        int m = e / 10, j = e - m * 10;
        float acc = 0.f;
        for (int k = 0; k < 64; ++k) acc += w_ih[m * 64 + k] * sWx[k * 10 + j];
        sWgi[e] = acc;
    }
    if (lane < 30) {
        float acc = b_ih[lane];
        for (int k = 0; k < 64; ++k) acc += w_ih[lane * 64 + k] * sbx[k];
        sbgi[lane] = acc;
    }
    __syncthreads();

    const float LOG2E = 1.4426950408889634f;
    const float S2    = 2.f * LOG2E;

    // ---- per-lane weights (feature fi), scalar duplicated into both halves ----
    v2f wr2[10], wz2[10], wi2[10], wh2[10], wo2[10];
    #pragma unroll
    for (int k = 0; k < 10; ++k) {
        float rk = -(sWgi[fi * 10 + k] + sWhh[fi * 10 + k]) * LOG2E;
        float zk = -(sWgi[(10 + fi) * 10 + k] + sWhh[(10 + fi) * 10 + k]) * LOG2E;
        float ik = sWgi[(20 + fi) * 10 + k] * S2;
        float hk = sWhh[(20 + fi) * 10 + k] * S2;
        float okw = l1_w[fi * 10 + k];
        wr2[k] = ok ? v2f{rk, rk}   : v2f{0.f, 0.f};
        wz2[k] = ok ? v2f{zk, zk}   : v2f{0.f, 0.f};
        wi2[k] = ok ? v2f{ik, ik}   : v2f{0.f, 0.f};
        wh2[k] = ok ? v2f{hk, hk}   : v2f{0.f, 0.f};
        wo2[k] = ok ? v2f{okw, okw} : v2f{0.f, 0.f};
    }
    const float br = ok ? -(sbgi[fi] + b_hh[fi]) * LOG2E : 0.f;
    const float bz = ok ? -(sbgi[10 + fi] + b_hh[10 + fi]) * LOG2E : 0.f;
    const float bi = ok ? sbgi[20 + fi] * S2 : 0.f;
    const float bh = ok ? b_hh[20 + fi] * S2 : 0.f;
    const float bo = ok ? l1_b[fi] : 0.f;
    const v2f BR2 = {br, br}, BZ2 = {bz, bz}, BI2 = {bi, bi},
              BH2 = {bh, bh}, BO2 = {bo, bo};
    // t=0 peel biases (gi = b_ih only)
    const float br0_ = ok ? -(b_ih[fi] + b_hh[fi]) * LOG2E : 0.f;
    const float bz0_ = ok ? -(b_ih[10 + fi] + b_hh[10 + fi]) * LOG2E : 0.f;
    const float bni0 = ok ? b_ih[20 + fi] * S2 : 0.f;

    // ---- initial h for both batches (f>=10 stays exactly 0) ----
    float hA = ok ? hidden[(size_t)bA * HID + f] : 0.f;
    float hB = ok ? hidden[(size_t)bB * HID + f] : 0.f;

    float* pbA = out + (size_t)bA * (STEPS * HID) + (size_t)(STEPS - 1) * HID + f;
    float* pbB = out + (size_t)bB * (STEPS * HID) + (size_t)(STEPS - 1) * HID + f;
    float* sRow = &sHp[g * 36];           // 18 v2f = 144B stride per group

    // ---- t = 0 peel (gi = b_ih only; x_0 = 0) per batch half ----
    auto peel0 = [&](float& h) {
        float ha[10];
        ha[0] = swz<0>(h); ha[1] = swz<1>(h); ha[2] = swz<2>(h);
        ha[3] = swz<3>(h); ha[4] = swz<4>(h); ha[5] = swz<5>(h);
        ha[6] = swz<6>(h); ha[7] = swz<7>(h); ha[8] = swz<8>(h);
        ha[9] = swz<9>(h);
        float pr = 0.f, pz = 0.f, ph = 0.f;
        #pragma unroll
        for (int k = 0; k < 10; ++k) {
            pr += sWhh[fi * 10 + k] * ha[k];
            pz += sWhh[(10 + fi) * 10 + k] * ha[k];
            ph += sWhh[(20 + fi) * 10 + k] * ha[k];
        }
        float vr = br0_ - pr * LOG2E;
        float vz = bz0_ - pz * LOG2E;
        float r = __builtin_amdgcn_rcpf(1.f + __builtin_amdgcn_exp2f(vr));
        float z = __builtin_amdgcn_rcpf(1.f + __builtin_amdgcn_exp2f(vz));
        float y = bni0 + r * (ph * S2 + bh);
        float n = 1.f - 2.f * __builtin_amdgcn_rcpf(1.f + __builtin_amdgcn_exp2f(y));
        h = ok ? (n + z * (h - n)) : 0.f;
    };
    peel0(hA);
    peel0(hB);

    // ---- t = 1 .. 511 : pair-packed; 1 write_b64 + 5 broadcast b128 reads ----
    #pragma unroll 1
    for (int t = 1; t < STEPS; ++t) {
        *(v2f*)(sRow + 2 * f) = v2f{hA, hB};      // stage pair (all 64 lanes)
        __builtin_amdgcn_wave_barrier();          // keep write->reads ordered
        __builtin_amdgcn_sched_barrier(0);
        v4f q0 = *(const v4f*)(sRow);             // {hA0,hB0,hA1,hB1}
        v4f q1 = *(const v4f*)(sRow + 4);         // k=2,3
        v4f q2 = *(const v4f*)(sRow + 8);         // k=4,5
        v4f q3 = *(const v4f*)(sRow + 12);        // k=6,7
        v4f q4 = *(const v4f*)(sRow + 16);        // k=8,9

        v2f p0 = __builtin_shufflevector(q0, q0, 0, 1);
        v2f p1 = __builtin_shufflevector(q0, q0, 2, 3);
        v2f p2 = __builtin_shufflevector(q1, q1, 0, 1);
        v2f p3 = __builtin_shufflevector(q1, q1, 2, 3);
        v2f p4 = __builtin_shufflevector(q2, q2, 0, 1);
        v2f p5 = __builtin_shufflevector(q2, q2, 2, 3);
        v2f p6 = __builtin_shufflevector(q3, q3, 0, 1);
        v2f p7 = __builtin_shufflevector(q3, q3, 2, 3);
        v2f p8 = __builtin_shufflevector(q4, q4, 0, 1);
        v2f p9 = __builtin_shufflevector(q4, q4, 2, 3);

        // 5 families x 10 k, even/odd partial chains (depth 5 + combine)
        v2f arE = wr2[0] * p0 + BR2;   v2f arO = wr2[1] * p1;
        v2f azE = wz2[0] * p0 + BZ2;   v2f azO = wz2[1] * p1;
        v2f aiE = wi2[0] * p0 + BI2;   v2f aiO = wi2[1] * p1;
        v2f ahE = wh2[0] * p0 + BH2;   v2f ahO = wh2[1] * p1;
        v2f aoE = wo2[0] * p0 + BO2;   v2f aoO = wo2[1] * p1;
        arE += wr2[2] * p2;  arO += wr2[3] * p3;
        azE += wz2[2] * p2;  azO += wz2[3] * p3;
        aiE += wi2[2] * p2;  aiO += wi2[3] * p3;
        ahE += wh2[2] * p2;  ahO += wh2[3] * p3;
        aoE += wo2[2] * p2;  aoO += wo2[3] * p3;
        arE += wr2[4] * p4;  arO += wr2[5] * p5;
        azE += wz2[4] * p4;  azO += wz2[5] * p5;
        aiE += wi2[4] * p4;  aiO += wi2[5] * p5;
        ahE += wh2[4] * p4;  ahO += wh2[5] * p5;
        aoE += wo2[4] * p4;  aoO += wo2[5] * p5;
        arE += wr2[6] * p6;  arO += wr2[7] * p7;
        azE += wz2[6] * p6;  azO += wz2[7] * p7;
        aiE += wi2[6] * p6;  aiO += wi2[7] * p7;
        ahE += wh2[6] * p6;  ahO += wh2[7] * p7;
        aoE += wo2[6] * p6;  aoO += wo2[7] * p7;
        arE += wr2[8] * p8;  arO += wr2[9] * p9;
        azE += wz2[8] * p8;  azO += wz2[9] * p9;
        aiE += wi2[8] * p8;  aiO += wi2[9] * p9;
        ahE += wh2[8] * p8;  ahO += wh2[9] * p9;
        aoE += wo2[8] * p8;  aoO += wo2[9] * p9;
        v2f ar = arE + arO;
        v2f az = azE + azO;
        v2f ai = aiE + aiO;
        v2f ah = ahE + ahO;
        v2f ao = aoE + aoO;           // = {oA, oB} = o_{t-1}

        // trans tails per half, interleaved (fused z/n, single rcp each):
        //   h' = (ez*(en-1) + h*(en+1)) / ((en+1)*(1+ez))
        float erA = __builtin_amdgcn_exp2f(ar.x);
        float erB = __builtin_amdgcn_exp2f(ar.y);
        float rA  = __builtin_amdgcn_rcpf(1.f + erA);
        float rB  = __builtin_amdgcn_rcpf(1.f + erB);
        float ezA = __builtin_amdgcn_exp2f(az.x);
        float ezB = __builtin_amdgcn_exp2f(az.y);
        float yA  = __builtin_fmaf(rA, ah.x, ai.x);
        float yB  = __builtin_fmaf(rB, ah.y, ai.y);
        float enA = __builtin_amdgcn_exp2f(yA);
        float enB = __builtin_amdgcn_exp2f(yB);
        float pA  = enA * ezA;             float pB  = enB * ezB;
        float uA  = pA + (hA - ezA);       float uB  = pB + (hB - ezB);
        float numA = __builtin_fmaf(hA, enA, uA);
        float numB = __builtin_fmaf(hB, enB, uB);
        float denA = (pA + (enA + ezA)) + 1.f;
        float denB = (pB + (enB + ezB)) + 1.f;
        hA = numA * __builtin_amdgcn_rcpf(denA);   // padded lanes stay 0
        hB = numB * __builtin_amdgcn_rcpf(denB);

        if (ok) { pbA[0] = ao.x; pbB[0] = ao.y; }  // store o_{t-1}
        pbA -= HID; pbB -= HID;
    }

    // ---- epilogue: o_511 = l1(h_512) at position 0 ----
    {
        *(v2f*)(sRow + 2 * f) = v2f{hA, hB};
        __builtin_amdgcn_wave_barrier();
        __builtin_amdgcn_sched_barrier(0);
        v4f q0 = *(const v4f*)(sRow);
        v4f q1 = *(const v4f*)(sRow + 4);
        v4f q2 = *(const v4f*)(sRow + 8);
        v4f q3 = *(const v4f*)(sRow + 12);
        v4f q4 = *(const v4f*)(sRow + 16);
        v2f ao = wo2[0] * __builtin_shufflevector(q0, q0, 0, 1) + BO2;
        ao += wo2[1] * __builtin_shufflevector(q0, q0, 2, 3);
        ao += wo2[2] * __builtin_shufflevector(q1, q1, 0, 1);
        ao += wo2[3] * __builtin_shufflevector(q1, q1, 2, 3);
        ao += wo2[4] * __builtin_shufflevector(q2, q2, 0, 1);
        ao += wo2[5] * __builtin_shufflevector(q2, q2, 2, 3);
        ao += wo2[6] * __builtin_shufflevector(q3, q3, 0, 1);
        ao += wo2[7] * __builtin_shufflevector(q3, q3, 2, 3);
        ao += wo2[8] * __builtin_shufflevector(q4, q4, 0, 1);
        ao += wo2[9] * __builtin_shufflevector(q4, q4, 2, 3);
        if (ok) { pbA[0] = ao.x; pbB[0] = ao.y; }
    }
}

extern "C" void kernel_launch(void* const* d_in, const int* in_sizes, int n_in,
                              void* d_out, int out_size, void* d_ws, size_t ws_size,
                              hipStream_t stream) {
    (void)in_sizes; (void)n_in; (void)d_ws; (void)ws_size; (void)out_size;
    dim3 grid(1024), block(64);   // 8 batches/wave (pair-packed), 1024 waves = 1/SIMD
    gru_decoder_kernel<<<grid, block, 0, stream>>>(
        (const float*)d_in[0], (const float*)d_in[1], (const float*)d_in[2],
        (const float*)d_in[3], (const float*)d_in[4], (const float*)d_in[5],
        (const float*)d_in[6], (const float*)d_in[7], (const float*)d_in[8],
        (float*)d_out);
}